// Round 1
// baseline (25703.467 us; speedup 1.0000x reference)
//
#include <hip/hip_runtime.h>
#include <math.h>

#define T_STEPS 4096
#define RES     2048
#define NF      8
#define NR      8
#define K_WG    128     // workgroups in recurrence kernel (RES / S_COLS)
#define S_COLS  16      // columns of x_new owned per WG
#define NTHR    256     // 4 waves
#define RPL     32      // rows per lane (RES / 64)
#define CPW     4       // cols per wave (S_COLS / 4 waves)

// ---------------------------------------------------------------------------
// drive[t][j] = Win[0][j] + sum_f inp[t][f] * Win[1+f][j]
__global__ void k_drive(const float* __restrict__ inp, const float* __restrict__ Win,
                        float* __restrict__ drive) {
    int idx = blockIdx.x * blockDim.x + threadIdx.x;   // [0, T*RES)
    int t = idx >> 11;            // / RES
    int j = idx & (RES - 1);
    float d = Win[j];
#pragma unroll
    for (int f = 0; f < NF; ++f)
        d += inp[t * NF + f] * Win[(1 + f) * RES + j];
    drive[idx] = d;
}

// ---------------------------------------------------------------------------
// init: X[0] = 0, cnt[0] = K_WG (ready), cnt[1..T] = 0
__global__ void k_init(float* __restrict__ X, unsigned* __restrict__ cnt) {
    int tid = threadIdx.x + blockIdx.x * blockDim.x;
    int stride = blockDim.x * gridDim.x;
    for (int i = tid; i < RES; i += stride) X[i] = 0.f;
    for (int i = tid; i <= T_STEPS; i += stride) cnt[i] = (i == 0) ? K_WG : 0u;
}

// ---------------------------------------------------------------------------
// Persistent recurrence kernel. W register-resident: WG k owns columns
// [16k,16k+16); wave w owns 4 of them; lane l owns rows [32l,32l+32).
// Sync: cnt[t]==K_WG means X[t] fully written (agent-scope acquire/release).
__global__ __launch_bounds__(NTHR, 1) void k_recur(
        const float* __restrict__ W, const float* __restrict__ drive,
        float* __restrict__ X, unsigned* __restrict__ cnt) {
    const int k    = blockIdx.x;
    const int tid  = threadIdx.x;
    const int wave = tid >> 6;
    const int lane = tid & 63;
    const int col0 = k * S_COLS + wave * CPW;
    const int row0 = lane * RPL;

    // Load W fragment into registers: Wr[m] = W[row0+m][col0..col0+4)
    float4 Wr[RPL];
#pragma unroll
    for (int m = 0; m < RPL; ++m)
        Wr[m] = *reinterpret_cast<const float4*>(&W[(size_t)(row0 + m) * RES + col0]);

    for (int t = 0; t < T_STEPS; ++t) {
        if (tid == 0) {
            while (__hip_atomic_load(&cnt[t], __ATOMIC_ACQUIRE,
                                     __HIP_MEMORY_SCOPE_AGENT) < K_WG)
                __builtin_amdgcn_s_sleep(1);
        }
        __syncthreads();   // all waves wait; acquire in lane0 invalidated L1/L2

        const float* xrow = X + (size_t)t * RES;
        float4 xr[RPL / 4];
#pragma unroll
        for (int q = 0; q < RPL / 4; ++q)
            xr[q] = *reinterpret_cast<const float4*>(&xrow[row0 + q * 4]);

        float a0 = 0.f, a1 = 0.f, a2 = 0.f, a3 = 0.f;
#pragma unroll
        for (int q = 0; q < RPL / 4; ++q) {
            float4 xv = xr[q];
            float4 w0 = Wr[q * 4 + 0], w1 = Wr[q * 4 + 1],
                   w2 = Wr[q * 4 + 2], w3 = Wr[q * 4 + 3];
            a0 += xv.x * w0.x; a1 += xv.x * w0.y; a2 += xv.x * w0.z; a3 += xv.x * w0.w;
            a0 += xv.y * w1.x; a1 += xv.y * w1.y; a2 += xv.y * w1.z; a3 += xv.y * w1.w;
            a0 += xv.z * w2.x; a1 += xv.z * w2.y; a2 += xv.z * w2.z; a3 += xv.z * w2.w;
            a0 += xv.w * w3.x; a1 += xv.w * w3.y; a2 += xv.w * w3.z; a3 += xv.w * w3.w;
        }
        // 64-lane reduction (all lanes end with the full sums)
#pragma unroll
        for (int off = 32; off >= 1; off >>= 1) {
            a0 += __shfl_xor(a0, off, 64);
            a1 += __shfl_xor(a1, off, 64);
            a2 += __shfl_xor(a2, off, 64);
            a3 += __shfl_xor(a3, off, 64);
        }
        if (lane < CPW) {
            int col = col0 + lane;
            float z  = lane == 0 ? a0 : lane == 1 ? a1 : lane == 2 ? a2 : a3;
            float xo = xrow[col];
            float xn = 0.7f * xo + 0.3f * tanhf(drive[(size_t)t * RES + col] + z);
            __hip_atomic_store(&X[(size_t)(t + 1) * RES + col], xn,
                               __ATOMIC_RELAXED, __HIP_MEMORY_SCOPE_AGENT);
        }
        __syncthreads();   // drains each wave's stores (vmcnt(0) before s_barrier)
        if (tid == 0)
            __hip_atomic_fetch_add(&cnt[t + 1], 1u, __ATOMIC_RELEASE,
                                   __HIP_MEMORY_SCOPE_AGENT);
    }
}

// ---------------------------------------------------------------------------
// Y[t][r] = Wout[0][r] + sum_f inp[t][f]*Wout[1+f][r] + sum_j X[t+1][j]*Wout[9+j][r]
__global__ void k_readout(const float* __restrict__ inp, const float* __restrict__ Wout,
                          const float* __restrict__ X, float* __restrict__ Y) {
    int t   = blockIdx.x;
    int tid = threadIdx.x;
    int r   = tid & (NR - 1);
    int g   = tid >> 3;                    // 32 groups of 64 j's
    const float* x = X + (size_t)(t + 1) * RES;
    float p = 0.f;
#pragma unroll 4
    for (int m = 0; m < RES / 32; ++m) {
        int j = g * (RES / 32) + m;
        p += x[j] * Wout[(size_t)(1 + NF + j) * NR + r];
    }
    __shared__ float red[NTHR];
    red[tid] = p;
    __syncthreads();
    for (int s = NTHR / 2; s >= NR; s >>= 1) {
        if (tid < s) red[tid] += red[tid + s];
        __syncthreads();
    }
    if (tid < NR) {
        float y = Wout[tid];
#pragma unroll
        for (int f = 0; f < NF; ++f)
            y += inp[t * NF + f] * Wout[(1 + f) * NR + tid];
        Y[t * NR + tid] = y + red[tid];
    }
}

// ---------------------------------------------------------------------------
extern "C" void kernel_launch(void* const* d_in, const int* in_sizes, int n_in,
                              void* d_out, int out_size, void* d_ws, size_t ws_size,
                              hipStream_t stream) {
    const float* inp  = (const float*)d_in[0];   // (T, 8)
    const float* Win  = (const float*)d_in[1];   // (9, 2048)
    const float* W    = (const float*)d_in[2];   // (2048, 2048)
    const float* Wout = (const float*)d_in[3];   // (2057, 8)
    float* Y = (float*)d_out;                    // (T, 8)

    float*    drive = (float*)d_ws;                                   // 32 MB
    float*    X     = drive + (size_t)T_STEPS * RES;                  // 32 MB
    unsigned* cnt   = (unsigned*)(X + (size_t)(T_STEPS + 1) * RES);   // 16 KB

    k_init<<<64, 256, 0, stream>>>(X, cnt);
    k_drive<<<(T_STEPS * RES) / NTHR, NTHR, 0, stream>>>(inp, Win, drive);
    k_recur<<<K_WG, NTHR, 0, stream>>>(W, drive, X, cnt);
    k_readout<<<T_STEPS, NTHR, 0, stream>>>(inp, Wout, X, Y);
}

// Round 2
// 14311.118 us; speedup vs baseline: 1.7960x; 1.7960x over previous
//
#include <hip/hip_runtime.h>
#include <math.h>

#define T_STEPS 4096
#define RES     2048
#define NF      8
#define NR      8
#define K_WG    128      // 128 WGs x 4 waves = 512 waves; each wave owns 4 columns
#define NTHR    256
#define SENTINEL 2.0f    // reachable |x| < 1 strictly; 2.0 is unreachable

// ---------------------------------------------------------------------------
// drive[t][j] = Win[0][j] + sum_f inp[t][f] * Win[1+f][j]
__global__ void k_drive(const float* __restrict__ inp, const float* __restrict__ Win,
                        float* __restrict__ drive) {
    int idx = blockIdx.x * blockDim.x + threadIdx.x;   // [0, T*RES)
    int t = idx >> 11;
    int j = idx & (RES - 1);
    float d = Win[j];
#pragma unroll
    for (int f = 0; f < NF; ++f)
        d += inp[t * NF + f] * Win[(1 + f) * RES + j];
    drive[idx] = d;
}

// ---------------------------------------------------------------------------
// X[0][:] = 0 (initial state, valid); X[1..T][:] = SENTINEL (unwritten)
__global__ void k_init(float* __restrict__ X) {
    int tid = threadIdx.x + blockIdx.x * blockDim.x;
    int stride = blockDim.x * gridDim.x;
    const int total = (T_STEPS + 1) * RES;
    for (int i = tid; i < total; i += stride)
        X[i] = (i < RES) ? 0.f : SENTINEL;
}

// ---------------------------------------------------------------------------
// Persistent dataflow recurrence. No barriers, no flags: consumers poll the
// X row itself for sentinel-free data. Wave g owns columns [4g, 4g+4);
// lane l owns rows {l, l+64, ..., l+31*64} (coalesced poll loads).
// W fragment (128 floats/lane) pinned in VGPRs via asm.
__global__ __launch_bounds__(NTHR, 1) void k_recur(
        const float* __restrict__ W, const float* __restrict__ drive,
        float* __restrict__ X) {
    const int tid  = threadIdx.x;
    const int wave = tid >> 6;
    const int lane = tid & 63;
    const int g    = blockIdx.x * 4 + wave;   // [0, 512)
    const int c0   = g * 4;                   // this wave's 4 output columns

    // Load W fragment: Wr[i] = W[i*64+lane][c0 .. c0+4)
    float4 Wr[32];
#pragma unroll
    for (int i = 0; i < 32; ++i)
        Wr[i] = *reinterpret_cast<const float4*>(&W[(size_t)(i * 64 + lane) * RES + c0]);
    // Pin in registers: block the compiler from sinking/rematerializing the
    // loads inside the t-loop (round-1 failure mode: VGPR_Count=84 -> W
    // re-streamed from LLC every step).
#pragma unroll
    for (int i = 0; i < 32; ++i)
        asm volatile("" : "+v"(Wr[i].x), "+v"(Wr[i].y), "+v"(Wr[i].z), "+v"(Wr[i].w));

    for (int t = 0; t < T_STEPS; ++t) {
        const float* xrow = X + (size_t)t * RES;

        // Independent of x_t: prefetch drive for this wave's columns.
        float dr = 0.f;
        if (lane < 4) dr = drive[(size_t)t * RES + c0 + lane];

        // Poll row t until every element this lane needs is sentinel-free.
        // Relaxed agent-scope loads bypass L1/L2 (cross-XCD visibility).
        float xv[32];
        for (;;) {
#pragma unroll
            for (int i = 0; i < 32; ++i)
                xv[i] = __hip_atomic_load(&xrow[i * 64 + lane],
                                          __ATOMIC_RELAXED, __HIP_MEMORY_SCOPE_AGENT);
            float m = 0.f;
#pragma unroll
            for (int i = 0; i < 32; ++i)
                m = fmaxf(m, __builtin_fabsf(xv[i]));
            if (__all(m < 1.5f)) break;   // whole row verified across the wave
            __builtin_amdgcn_s_sleep(1);
        }

        // Row t is fully published; issue old-x load early (latency hidden
        // under the FMA + reduce below).
        float xo = 0.f;
        if (lane < 4)
            xo = __hip_atomic_load(&xrow[c0 + lane],
                                   __ATOMIC_RELAXED, __HIP_MEMORY_SCOPE_AGENT);

        // z[c0+j] = sum_i x[i*64+lane] * W[i*64+lane][c0+j], partial per lane
        float a0 = 0.f, a1 = 0.f, a2 = 0.f, a3 = 0.f;
#pragma unroll
        for (int i = 0; i < 32; ++i) {
            float xs = xv[i];
            float4 w = Wr[i];
            a0 = fmaf(xs, w.x, a0);
            a1 = fmaf(xs, w.y, a1);
            a2 = fmaf(xs, w.z, a2);
            a3 = fmaf(xs, w.w, a3);
        }
        // 64-lane butterfly: all lanes end with the 4 full column sums.
#pragma unroll
        for (int off = 32; off >= 1; off >>= 1) {
            a0 += __shfl_xor(a0, off, 64);
            a1 += __shfl_xor(a1, off, 64);
            a2 += __shfl_xor(a2, off, 64);
            a3 += __shfl_xor(a3, off, 64);
        }

        if (lane < 4) {
            float a  = lane == 0 ? a0 : lane == 1 ? a1 : lane == 2 ? a2 : a3;
            float xn = 0.7f * xo + 0.3f * tanhf(dr + a);
            // Publish: single coalesced 16B (4 lanes x 1 dword), fire-and-forget.
            __hip_atomic_store(&X[(size_t)(t + 1) * RES + c0 + lane], xn,
                               __ATOMIC_RELAXED, __HIP_MEMORY_SCOPE_AGENT);
        }
    }
}

// ---------------------------------------------------------------------------
// Y[t][r] = Wout[0][r] + sum_f inp[t][f]*Wout[1+f][r] + sum_j X[t+1][j]*Wout[9+j][r]
__global__ void k_readout(const float* __restrict__ inp, const float* __restrict__ Wout,
                          const float* __restrict__ X, float* __restrict__ Y) {
    int t   = blockIdx.x;
    int tid = threadIdx.x;
    int r   = tid & (NR - 1);
    int gph = tid >> 3;                    // 32 groups
    const float* x = X + (size_t)(t + 1) * RES;
    float p = 0.f;
#pragma unroll 4
    for (int m = 0; m < RES / 32; ++m) {
        int j = gph * (RES / 32) + m;
        p += x[j] * Wout[(size_t)(1 + NF + j) * NR + r];
    }
    __shared__ float red[NTHR];
    red[tid] = p;
    __syncthreads();
    for (int s = NTHR / 2; s >= NR; s >>= 1) {
        if (tid < s) red[tid] += red[tid + s];
        __syncthreads();
    }
    if (tid < NR) {
        float y = Wout[tid];
#pragma unroll
        for (int f = 0; f < NF; ++f)
            y += inp[t * NF + f] * Wout[(1 + f) * NR + tid];
        Y[t * NR + tid] = y + red[tid];
    }
}

// ---------------------------------------------------------------------------
extern "C" void kernel_launch(void* const* d_in, const int* in_sizes, int n_in,
                              void* d_out, int out_size, void* d_ws, size_t ws_size,
                              hipStream_t stream) {
    const float* inp  = (const float*)d_in[0];   // (T, 8)
    const float* Win  = (const float*)d_in[1];   // (9, 2048)
    const float* W    = (const float*)d_in[2];   // (2048, 2048)
    const float* Wout = (const float*)d_in[3];   // (2057, 8)
    float* Y = (float*)d_out;                    // (T, 8)

    float* drive = (float*)d_ws;                            // 32 MB
    float* X     = drive + (size_t)T_STEPS * RES;           // 32 MB + 8 KB

    k_init<<<2048, NTHR, 0, stream>>>(X);
    k_drive<<<(T_STEPS * RES) / NTHR, NTHR, 0, stream>>>(inp, Win, drive);
    k_recur<<<K_WG, NTHR, 0, stream>>>(W, drive, X);
    k_readout<<<T_STEPS, NTHR, 0, stream>>>(inp, Wout, X, Y);
}